// Round 1
// baseline (1032.420 us; speedup 1.0000x reference)
//
#include <hip/hip_runtime.h>
#include <hip/hip_bf16.h>
#include <stddef.h>

// Problem constants
constexpr int E_ = 8;
constexpr int C_ = 1024;
constexpr int M_ = 2048;
constexpr int H_ = 8192;
constexpr int O_ = 2048;

typedef __bf16 bf16;
typedef __bf16 bf16x4 __attribute__((ext_vector_type(4)));
typedef __bf16 bf16x8 __attribute__((ext_vector_type(8)));
typedef float  f32x4  __attribute__((ext_vector_type(4)));

__device__ __forceinline__ void load_lds16(const void* g, void* l) {
    // async global->LDS, 16B per lane; LDS dest = wave-uniform base + lane*16
    __builtin_amdgcn_global_load_lds((const __attribute__((address_space(1))) void*)g,
                                     (__attribute__((address_space(3))) void*)l,
                                     16, 0, 0);
}

// ---------------------------------------------------------------------------
// GEMM1: y1[e,c,h] = relu( sum_m x[e,c,m]*w1[e,h,m] + b1[e,h] ), bf16 output.
// fp32 inputs -> reg-staged conversion to bf16 in LDS (padded stride 40).
// BM=BN=128, BK=32, 256 threads = 4 waves (2x2), 64x64 per wave.
// ---------------------------------------------------------------------------
__global__ __launch_bounds__(256, 2)
void gemm1_relu(const float* __restrict__ X,   // [E, C, M]
                const float* __restrict__ W1,  // [E, H, M]
                const float* __restrict__ B1,  // [E, H]
                bf16* __restrict__ Y1,         // [gridDim.z, C, H]
                int e0)
{
    const int e  = e0 + blockIdx.z;
    const int bn = blockIdx.x;          // h tile
    const int bm = blockIdx.y;          // c tile
    const int tid  = threadIdx.x;
    const int lane = tid & 63;
    const int wv   = tid >> 6;
    const int wr   = wv >> 1;
    const int wc   = wv & 1;

    __shared__ bf16 Asm[128][40];       // pad to 40 bf16 (80B): balances write banks, keeps 16B-aligned b128 reads
    __shared__ bf16 Bsm[128][40];

    const float* Ae = X  + (size_t)e * C_ * M_ + (size_t)bm * 128 * M_;
    const float* Be = W1 + (size_t)e * H_ * M_ + (size_t)bn * 128 * M_;

    f32x4 acc[4][4];
#pragma unroll
    for (int i = 0; i < 4; ++i)
#pragma unroll
        for (int j = 0; j < 4; ++j) acc[i][j] = (f32x4){0.f, 0.f, 0.f, 0.f};

    const int srow = tid >> 3;          // 0..31
    const int skq  = tid & 7;           // 0..7  (float4 chunk along K)
    const int fr = lane & 15, fq = lane >> 4;

    for (int k0 = 0; k0 < M_; k0 += 32) {
        __syncthreads();                // prev iter's frag reads done before overwrite
#pragma unroll
        for (int p = 0; p < 4; ++p) {
            int r = p * 32 + srow;
            f32x4 va = *(const f32x4*)(Ae + (size_t)r * M_ + k0 + skq * 4);
            f32x4 vb = *(const f32x4*)(Be + (size_t)r * M_ + k0 + skq * 4);
            bf16x4 ha, hb;
#pragma unroll
            for (int q = 0; q < 4; ++q) { ha[q] = (bf16)va[q]; hb[q] = (bf16)vb[q]; }
            *(bf16x4*)(&Asm[r][skq * 4]) = ha;   // ds_write_b64
            *(bf16x4*)(&Bsm[r][skq * 4]) = hb;
        }
        __syncthreads();

        bf16x8 af[4], bfr[4];
#pragma unroll
        for (int m = 0; m < 4; ++m)
            af[m] = *(const bf16x8*)(&Asm[wr * 64 + m * 16 + fr][fq * 8]);
#pragma unroll
        for (int n = 0; n < 4; ++n)
            bfr[n] = *(const bf16x8*)(&Bsm[wc * 64 + n * 16 + fr][fq * 8]);
#pragma unroll
        for (int m = 0; m < 4; ++m)
#pragma unroll
            for (int n = 0; n < 4; ++n)
                acc[m][n] = __builtin_amdgcn_mfma_f32_16x16x32_bf16(af[m], bfr[n], acc[m][n], 0, 0, 0);
    }

    // epilogue: bias + relu -> bf16
    const size_t ybase = (size_t)blockIdx.z * C_ * H_;
#pragma unroll
    for (int n = 0; n < 4; ++n) {
        const int col = bn * 128 + wc * 64 + n * 16 + fr;
        const float bb = B1[(size_t)e * H_ + col];
#pragma unroll
        for (int m = 0; m < 4; ++m) {
#pragma unroll
            for (int j = 0; j < 4; ++j) {
                float v = acc[m][n][j] + bb;
                v = v > 0.f ? v : 0.f;
                const int row = bm * 128 + wr * 64 + m * 16 + fq * 4 + j;
                Y1[ybase + (size_t)row * H_ + col] = (bf16)v;
            }
        }
    }
}

// ---------------------------------------------------------------------------
// Transpose+convert: W2 [E, H, O] fp32 -> W2t [gridDim.z, O, H] bf16
// 64x64 tiles through LDS; coalesced fp32 reads, coalesced 8B bf16 writes.
// ---------------------------------------------------------------------------
__global__ __launch_bounds__(256)
void transpose_w2(const float* __restrict__ W2, bf16* __restrict__ W2t, int e0)
{
    const int e  = e0 + blockIdx.z;
    const int oo = blockIdx.x;  // O/64
    const int ho = blockIdx.y;  // H/64
    const int tid = threadIdx.x;

    __shared__ bf16 t[64][68];  // pad 68: even stride (136B), 8B-aligned 4-elem reads

    const float* src = W2 + (size_t)e * H_ * O_ + (size_t)(ho * 64) * O_ + oo * 64;
#pragma unroll
    for (int p = 0; p < 4; ++p) {
        const int h  = p * 16 + (tid >> 4);
        const int o4 = (tid & 15) * 4;
        f32x4 v = *(const f32x4*)(src + (size_t)h * O_ + o4);
#pragma unroll
        for (int q = 0; q < 4; ++q) t[o4 + q][h] = (bf16)v[q];
    }
    __syncthreads();

    bf16* dst = W2t + (size_t)blockIdx.z * O_ * H_ + (size_t)(oo * 64) * H_ + ho * 64;
#pragma unroll
    for (int p = 0; p < 4; ++p) {
        const int o  = p * 16 + (tid >> 4);
        const int h4 = (tid & 15) * 4;
        bf16x4 v = *(const bf16x4*)(&t[o][h4]);
        *(bf16x4*)(dst + (size_t)o * H_ + h4) = v;
    }
}

// ---------------------------------------------------------------------------
// GEMM2: out[e,c,o] = sum_h y1[e,c,h]*w2t[e,o,h] + b2[e,o], fp32 output.
// Pure bf16 inputs -> global_load_lds width-16 staging, linear [128][32] LDS.
// ---------------------------------------------------------------------------
__global__ __launch_bounds__(256, 2)
void gemm2_bias(const bf16* __restrict__ A,    // [gridDim.z, C, H]  y1
                const bf16* __restrict__ Bt,   // [gridDim.z, O, H]  w2 transposed
                const float* __restrict__ B2,  // [E, O]
                float* __restrict__ Out,       // [E, C, O]
                int e0)
{
    const int e  = e0 + blockIdx.z;
    const int bn = blockIdx.x;          // o tile
    const int bm = blockIdx.y;          // c tile
    const int tid  = threadIdx.x;
    const int lane = tid & 63;
    const int wv   = tid >> 6;
    const int wr   = wv >> 1;
    const int wc   = wv & 1;

    __shared__ bf16 Asm[128][32];       // linear: required by global_load_lds; 64B rows = bank-balanced
    __shared__ bf16 Bsm[128][32];

    const bf16* Ae = A  + (size_t)blockIdx.z * C_ * H_ + (size_t)bm * 128 * H_;
    const bf16* Be = Bt + (size_t)blockIdx.z * O_ * H_ + (size_t)bn * 128 * H_;

    f32x4 acc[4][4];
#pragma unroll
    for (int i = 0; i < 4; ++i)
#pragma unroll
        for (int j = 0; j < 4; ++j) acc[i][j] = (f32x4){0.f, 0.f, 0.f, 0.f};

    const int fr = lane & 15, fq = lane >> 4;
    const int lrow = lane >> 2;         // 0..15 within 16-row chunk
    const int lkp  = lane & 3;          // 16B piece along K

    for (int k0 = 0; k0 < H_; k0 += 32) {
        __syncthreads();
#pragma unroll
        for (int i = 0; i < 2; ++i) {
            const int chunk = wv * 2 + i;           // 8 chunks of 16 rows
            const int row = chunk * 16 + lrow;
            const bf16* ga = Ae + (size_t)row * H_ + k0 + lkp * 8;
            const bf16* gb = Be + (size_t)row * H_ + k0 + lkp * 8;
            load_lds16(ga, ((bf16*)Asm) + chunk * 512 + lane * 8);
            load_lds16(gb, ((bf16*)Bsm) + chunk * 512 + lane * 8);
        }
        __syncthreads();                // drains vmcnt(0): staged data visible

        bf16x8 af[4], bfr[4];
#pragma unroll
        for (int m = 0; m < 4; ++m)
            af[m] = *(const bf16x8*)(&Asm[wr * 64 + m * 16 + fr][fq * 8]);
#pragma unroll
        for (int n = 0; n < 4; ++n)
            bfr[n] = *(const bf16x8*)(&Bsm[wc * 64 + n * 16 + fr][fq * 8]);
#pragma unroll
        for (int m = 0; m < 4; ++m)
#pragma unroll
            for (int n = 0; n < 4; ++n)
                acc[m][n] = __builtin_amdgcn_mfma_f32_16x16x32_bf16(af[m], bfr[n], acc[m][n], 0, 0, 0);
    }

    // epilogue: + bias, fp32 store
#pragma unroll
    for (int n = 0; n < 4; ++n) {
        const int col = bn * 128 + wc * 64 + n * 16 + fr;
        const float bb = B2[(size_t)e * O_ + col];
#pragma unroll
        for (int m = 0; m < 4; ++m) {
#pragma unroll
            for (int j = 0; j < 4; ++j) {
                const int row = bm * 128 + wr * 64 + m * 16 + fq * 4 + j;
                Out[(size_t)e * C_ * O_ + (size_t)row * O_ + col] = acc[m][n][j] + bb;
            }
        }
    }
}

// ---------------------------------------------------------------------------
extern "C" void kernel_launch(void* const* d_in, const int* in_sizes, int n_in,
                              void* d_out, int out_size, void* d_ws, size_t ws_size,
                              hipStream_t stream)
{
    const float* x  = (const float*)d_in[0];
    const float* w1 = (const float*)d_in[1];
    const float* b1 = (const float*)d_in[2];
    const float* w2 = (const float*)d_in[3];
    const float* b2 = (const float*)d_in[4];
    float* out = (float*)d_out;

    const size_t y1_full  = (size_t)E_ * C_ * H_ * sizeof(bf16);   // 128 MB
    const size_t w2t_full = (size_t)E_ * O_ * H_ * sizeof(bf16);   // 256 MB

    if (ws_size >= y1_full + w2t_full) {
        bf16* y1  = (bf16*)d_ws;
        bf16* w2t = (bf16*)((char*)d_ws + y1_full);
        transpose_w2<<<dim3(O_ / 64, H_ / 64, E_), 256, 0, stream>>>(w2, w2t, 0);
        gemm1_relu  <<<dim3(H_ / 128, C_ / 128, E_), 256, 0, stream>>>(x, w1, b1, y1, 0);
        gemm2_bias  <<<dim3(O_ / 128, C_ / 128, E_), 256, 0, stream>>>(y1, w2t, b2, out, 0);
    } else {
        // per-expert fallback: 16 MB y1 slice + 32 MB w2t slice = 48 MB
        bf16* y1  = (bf16*)d_ws;
        bf16* w2t = (bf16*)((char*)d_ws + (size_t)C_ * H_ * sizeof(bf16));
        for (int e = 0; e < E_; ++e) {
            transpose_w2<<<dim3(O_ / 64, H_ / 64, 1), 256, 0, stream>>>(w2, w2t, e);
            gemm1_relu  <<<dim3(H_ / 128, C_ / 128, 1), 256, 0, stream>>>(x, w1, b1, y1, e);
            gemm2_bias  <<<dim3(O_ / 128, C_ / 128, 1), 256, 0, stream>>>(y1, w2t, b2, out, e);
        }
    }
}

// Round 2
// 897.083 us; speedup vs baseline: 1.1509x; 1.1509x over previous
//
#include <hip/hip_runtime.h>
#include <hip/hip_bf16.h>
#include <stddef.h>

// Problem constants
constexpr int E_ = 8;
constexpr int C_ = 1024;
constexpr int M_ = 2048;
constexpr int H_ = 8192;
constexpr int O_ = 2048;

typedef __bf16 bf16;
typedef __bf16 bf16x4 __attribute__((ext_vector_type(4)));
typedef __bf16 bf16x8 __attribute__((ext_vector_type(8)));
typedef float  f32x4  __attribute__((ext_vector_type(4)));

#define GLOAD16(src, dst)                                                        \
    __builtin_amdgcn_global_load_lds(                                            \
        (const __attribute__((address_space(1))) void*)(src),                    \
        (__attribute__((address_space(3))) void*)(dst), 16, 0, 0)

// ---------------------------------------------------------------------------
// fp32 -> bf16 convert (grid-stride, 16B-read/16B-write per lane)
// ---------------------------------------------------------------------------
__global__ __launch_bounds__(256)
void cvt_f32_bf16(const float* __restrict__ in, bf16* __restrict__ out, size_t n)
{
    size_t i = ((size_t)blockIdx.x * blockDim.x + threadIdx.x) * 8;
    const size_t stride = (size_t)gridDim.x * blockDim.x * 8;
    for (; i < n; i += stride) {
        f32x4 v0 = *(const f32x4*)(in + i);
        f32x4 v1 = *(const f32x4*)(in + i + 4);
        bf16x8 o;
#pragma unroll
        for (int j = 0; j < 4; ++j) { o[j] = (bf16)v0[j]; o[j + 4] = (bf16)v1[j]; }
        *(bf16x8*)(out + i) = o;
    }
}

// ---------------------------------------------------------------------------
// Transpose+convert: W2 [E, H, O] fp32 -> W2t [gridDim.z, O, H] bf16
// ---------------------------------------------------------------------------
__global__ __launch_bounds__(256)
void transpose_w2(const float* __restrict__ W2, bf16* __restrict__ W2t, int e0)
{
    const int e  = e0 + blockIdx.z;
    const int oo = blockIdx.x;  // O/64
    const int ho = blockIdx.y;  // H/64
    const int tid = threadIdx.x;

    __shared__ bf16 t[64][68];

    const float* src = W2 + (size_t)e * H_ * O_ + (size_t)(ho * 64) * O_ + oo * 64;
#pragma unroll
    for (int p = 0; p < 4; ++p) {
        const int h  = p * 16 + (tid >> 4);
        const int o4 = (tid & 15) * 4;
        f32x4 v = *(const f32x4*)(src + (size_t)h * O_ + o4);
#pragma unroll
        for (int q = 0; q < 4; ++q) t[o4 + q][h] = (bf16)v[q];
    }
    __syncthreads();

    bf16* dst = W2t + (size_t)blockIdx.z * O_ * H_ + (size_t)(oo * 64) * H_ + ho * 64;
#pragma unroll
    for (int p = 0; p < 4; ++p) {
        const int o  = p * 16 + (tid >> 4);
        const int h4 = (tid & 15) * 4;
        bf16x4 v = *(const bf16x4*)(&t[o][h4]);
        *(bf16x4*)(dst + (size_t)o * H_ + h4) = v;
    }
}

// ---------------------------------------------------------------------------
// 256x256-tile grouped GEMM, BK=32, 4 LDS buffers (128 KiB dynamic), 512 thr.
// C[row,col] = sum_k A[row,k]*B[col,k] (+bias[col]) ; both A,B row-major, K
// contiguous. 8 waves = 2(M) x 4(N), wave tile 128x64, acc[8][4] f32x4.
//
// Pipeline: stage tile t+3 (4 x global_load_lds/thread) -> ds_read frags of
// tile t -> 32 MFMA -> s_waitcnt vmcnt(8) (own t+1 loads landed) -> s_barrier
// (cross-wave: t+1 fully landed; buf (t+1-? ) reads done -> reusable).
// One barrier + one counted vmcnt per 32-K tile; never drains to 0 mid-loop.
//
// LDS swizzle (T2): within each 1024B [16 rows x 32 k] subtile, 16B-chunk
// index c stored at c ^ ((row&15)>>2). Applied identically on the staging
// SOURCE address (gload_lds writes linearly) and the ds_read address ->
// fragment reads land 2 lanes/bank (free).
// ---------------------------------------------------------------------------
template<int KDIM, bool RELU_BF16>
__global__ __launch_bounds__(512, 2)
void gemm256(const bf16* __restrict__ A, const bf16* __restrict__ B,
             const float* __restrict__ bias, void* __restrict__ OutP,
             int nBM, int nBN)
{
    extern __shared__ char smem[];                  // 4 x 32768 B
    constexpr int K2  = KDIM * 2;                   // row stride bytes
    constexpr int NKT = KDIM / 32;                  // K-tiles

    const int tid  = threadIdx.x;
    const int lane = tid & 63;
    const int wid  = tid >> 6;
    const int wr = wid >> 2, wc = wid & 3;
    const int fr = lane & 15, fq = lane >> 4;

    // XCD-aware bijective block swizzle (nwg % 8 == 0 by construction)
    const int nwg = gridDim.x;
    const int cpx = nwg >> 3;
    const int b0  = blockIdx.x;
    const int wg  = (b0 & 7) * cpx + (b0 >> 3);
    const int per_e = nBM * nBN;
    const int e  = wg / per_e;
    const int rr = wg - e * per_e;
    const int bn = rr / nBM;
    const int bm = rr - bn * nBM;
    const int MROWS = nBM * 256;
    const int NROWS = nBN * 256;

    const char* Apan = (const char*)(A + (size_t)e * MROWS * KDIM + (size_t)bm * 256 * KDIM);
    const char* Bpan = (const char*)(B + (size_t)e * NROWS * KDIM + (size_t)bn * 256 * KDIM);

    // staging: thread covers LDS bytes p = i*8192 + tid*16 (i=0,1) of a 16KB
    // half; invert subtile swizzle to find the global (row, kbyte) source.
    int off_i[2];
#pragma unroll
    for (int i = 0; i < 2; ++i) {
        int p   = i * 8192 + tid * 16;
        int sub = p >> 10;
        int u   = p & 1023;
        u ^= ((u >> 8) & 3) << 4;                   // involution
        int row = sub * 16 + (u >> 6);
        off_i[i] = row * K2 + (u & 63);
    }
    const int ao0 = off_i[0], ao1 = off_i[1];
    const int ldso = tid * 16;
    const int laneoff = fr * 64 + ((fq ^ (fr >> 2)) & 3) * 16;   // swizzled read

    f32x4 acc[8][4];
#pragma unroll
    for (int m = 0; m < 8; ++m)
#pragma unroll
        for (int n = 0; n < 4; ++n) acc[m][n] = (f32x4){0.f, 0.f, 0.f, 0.f};

    auto stage = [&](int s) {
        char* lb = smem + (s & 3) * 32768;
        const char* ka = Apan + (size_t)s * 64;     // k0*2 bytes
        const char* kb = Bpan + (size_t)s * 64;
        GLOAD16(ka + ao0, lb + ldso);
        GLOAD16(ka + ao1, lb + 8192  + ldso);
        GLOAD16(kb + ao0, lb + 16384 + ldso);
        GLOAD16(kb + ao1, lb + 24576 + ldso);
    };

    // prologue: tiles 0,1,2 in flight (12 loads); wait tile0 (oldest 4)
    stage(0); stage(1); stage(2);
    asm volatile("s_waitcnt vmcnt(8)" ::: "memory");
    __builtin_amdgcn_s_barrier();
    __builtin_amdgcn_sched_barrier(0);

    for (int t = 0; t < NKT; ++t) {
        if (t + 3 < NKT) stage(t + 3);              // buf (t+3)&3 == (t-1)&3: freed at last barrier

        const char* Ab = smem + (t & 3) * 32768;
        const char* Bb = Ab + 16384;
        bf16x8 av[8], bv[4];
#pragma unroll
        for (int n = 0; n < 4; ++n)
            bv[n] = *(const bf16x8*)(Bb + (wc * 4 + n) * 1024 + laneoff);
#pragma unroll
        for (int m = 0; m < 8; ++m)
            av[m] = *(const bf16x8*)(Ab + (wr * 8 + m) * 1024 + laneoff);

        __builtin_amdgcn_s_setprio(1);
#pragma unroll
        for (int m = 0; m < 8; ++m)
#pragma unroll
            for (int n = 0; n < 4; ++n)
                acc[m][n] = __builtin_amdgcn_mfma_f32_16x16x32_bf16(av[m], bv[n], acc[m][n], 0, 0, 0);
        __builtin_amdgcn_s_setprio(0);

        if (t + 3 < NKT)      asm volatile("s_waitcnt vmcnt(8)" ::: "memory");
        else if (t + 2 < NKT) asm volatile("s_waitcnt vmcnt(4)" ::: "memory");
        else if (t + 1 < NKT) asm volatile("s_waitcnt vmcnt(0)" ::: "memory");
        if (t + 1 < NKT) {
            __builtin_amdgcn_s_barrier();
            __builtin_amdgcn_sched_barrier(0);
        }
    }

    // epilogue
    const int gr0 = bm * 256 + wr * 128;
    const int gc0 = bn * 256 + wc * 64;
    if constexpr (RELU_BF16) {
        bf16* Out = (bf16*)OutP;
#pragma unroll
        for (int n = 0; n < 4; ++n) {
            const int col = gc0 + n * 16 + fr;
            const float bb = bias[(size_t)e * NROWS + col];
#pragma unroll
            for (int m = 0; m < 8; ++m)
#pragma unroll
                for (int j = 0; j < 4; ++j) {
                    float v = acc[m][n][j] + bb;
                    v = v > 0.f ? v : 0.f;
                    const int row = gr0 + m * 16 + fq * 4 + j;
                    Out[((size_t)e * MROWS + row) * NROWS + col] = (bf16)v;
                }
        }
    } else {
        float* Out = (float*)OutP;
#pragma unroll
        for (int n = 0; n < 4; ++n) {
            const int col = gc0 + n * 16 + fr;
            const float bb = bias[(size_t)e * NROWS + col];
#pragma unroll
            for (int m = 0; m < 8; ++m)
#pragma unroll
                for (int j = 0; j < 4; ++j) {
                    const int row = gr0 + m * 16 + fq * 4 + j;
                    Out[((size_t)e * MROWS + row) * NROWS + col] = acc[m][n][j] + bb;
                }
        }
    }
}

// ---------------------------------------------------------------------------
extern "C" void kernel_launch(void* const* d_in, const int* in_sizes, int n_in,
                              void* d_out, int out_size, void* d_ws, size_t ws_size,
                              hipStream_t stream)
{
    const float* x  = (const float*)d_in[0];
    const float* w1 = (const float*)d_in[1];
    const float* b1 = (const float*)d_in[2];
    const float* w2 = (const float*)d_in[3];
    const float* b2 = (const float*)d_in[4];
    float* out = (float*)d_out;

    // allow 128 KiB dynamic LDS (idempotent; harmless under graph capture)
    (void)hipFuncSetAttribute(reinterpret_cast<const void*>(&gemm256<M_, true>),
                              hipFuncAttributeMaxDynamicSharedMemorySize, 131072);
    (void)hipFuncSetAttribute(reinterpret_cast<const void*>(&gemm256<H_, false>),
                              hipFuncAttributeMaxDynamicSharedMemorySize, 131072);

    const size_t xb_sz  = (size_t)E_ * C_ * M_ * sizeof(bf16);   //  32 MB
    const size_t w1b_sz = (size_t)E_ * H_ * M_ * sizeof(bf16);   // 256 MB
    const size_t w2t_sz = (size_t)E_ * O_ * H_ * sizeof(bf16);   // 256 MB
    const size_t y1_sz  = (size_t)E_ * C_ * H_ * sizeof(bf16);   // 128 MB

    if (ws_size >= xb_sz + w1b_sz + w2t_sz + y1_sz) {
        bf16* xb  = (bf16*)d_ws;
        bf16* w1b = (bf16*)((char*)d_ws + xb_sz);
        bf16* w2t = (bf16*)((char*)d_ws + xb_sz + w1b_sz);
        bf16* y1  = (bf16*)((char*)d_ws + xb_sz + w1b_sz + w2t_sz);

        cvt_f32_bf16<<<2048, 256, 0, stream>>>(x,  xb,  (size_t)E_ * C_ * M_);
        cvt_f32_bf16<<<2048, 256, 0, stream>>>(w1, w1b, (size_t)E_ * H_ * M_);
        transpose_w2<<<dim3(O_ / 64, H_ / 64, E_), 256, 0, stream>>>(w2, w2t, 0);

        // gemm1: [E,1024,2048] x [E,8192,2048]^T -> bf16 y1, fused bias+relu
        gemm256<M_, true><<<dim3(8 * 4 * (H_ / 256)), 512, 131072, stream>>>(
            xb, w1b, b1, y1, 4, H_ / 256);
        // gemm2: [E,1024,8192] x [E,2048,8192]^T -> fp32 out, fused bias
        gemm256<H_, false><<<dim3(8 * 4 * (O_ / 256)), 512, 131072, stream>>>(
            y1, w2t, b2, out, 4, O_ / 256);
    } else {
        // per-expert fallback: ~84 MB of ws
        bf16* xb  = (bf16*)d_ws;
        bf16* w1b = (bf16*)((char*)d_ws + xb_sz / E_);
        bf16* w2t = (bf16*)((char*)d_ws + (xb_sz + w1b_sz) / E_);
        bf16* y1  = (bf16*)((char*)d_ws + (xb_sz + w1b_sz + w2t_sz) / E_);
        for (int e = 0; e < E_; ++e) {
            cvt_f32_bf16<<<512, 256, 0, stream>>>(x + (size_t)e * C_ * M_,  xb,  (size_t)C_ * M_);
            cvt_f32_bf16<<<2048, 256, 0, stream>>>(w1 + (size_t)e * H_ * M_, w1b, (size_t)H_ * M_);
            transpose_w2<<<dim3(O_ / 64, H_ / 64, 1), 256, 0, stream>>>(w2, w2t, e);
            gemm256<M_, true><<<dim3(4 * (H_ / 256)), 512, 131072, stream>>>(
                xb, w1b, b1 + (size_t)e * H_, y1, 4, H_ / 256);
            gemm256<H_, false><<<dim3(4 * (O_ / 256)), 512, 131072, stream>>>(
                y1, w2t, b2 + (size_t)e * O_, out + (size_t)e * C_ * O_, 4, O_ / 256);
        }
    }
}

// Round 3
// 798.442 us; speedup vs baseline: 1.2930x; 1.1235x over previous
//
#include <hip/hip_runtime.h>
#include <hip/hip_bf16.h>
#include <stddef.h>

// Problem constants
constexpr int E_ = 8;
constexpr int C_ = 1024;
constexpr int M_ = 2048;
constexpr int H_ = 8192;
constexpr int O_ = 2048;

typedef __bf16 bf16;
typedef __bf16 bf16x4 __attribute__((ext_vector_type(4)));
typedef __bf16 bf16x8 __attribute__((ext_vector_type(8)));
typedef float  f32x4  __attribute__((ext_vector_type(4)));

#define GLOAD16(src, dst)                                                        \
    __builtin_amdgcn_global_load_lds(                                            \
        (const __attribute__((address_space(1))) void*)(src),                    \
        (__attribute__((address_space(3))) void*)(dst), 16, 0, 0)

#define BARRIER()  __builtin_amdgcn_s_barrier()
#define LGKM0()    do { asm volatile("s_waitcnt lgkmcnt(0)" ::: "memory");       \
                        __builtin_amdgcn_sched_barrier(0); } while (0)
#define VMCNT(n)   asm volatile("s_waitcnt vmcnt(" #n ")" ::: "memory")

// ---------------------------------------------------------------------------
// fp32 -> bf16 convert (grid-stride, 32B-read/16B-write per lane)
// ---------------------------------------------------------------------------
__global__ __launch_bounds__(256)
void cvt_f32_bf16(const float* __restrict__ in, bf16* __restrict__ out, size_t n)
{
    size_t i = ((size_t)blockIdx.x * blockDim.x + threadIdx.x) * 8;
    const size_t stride = (size_t)gridDim.x * blockDim.x * 8;
    for (; i < n; i += stride) {
        f32x4 v0 = *(const f32x4*)(in + i);
        f32x4 v1 = *(const f32x4*)(in + i + 4);
        bf16x8 o;
#pragma unroll
        for (int j = 0; j < 4; ++j) { o[j] = (bf16)v0[j]; o[j + 4] = (bf16)v1[j]; }
        *(bf16x8*)(out + i) = o;
    }
}

// ---------------------------------------------------------------------------
// Transpose+convert: W2 [E, H, O] fp32 -> W2t [gridDim.z, O, H] bf16
// ---------------------------------------------------------------------------
__global__ __launch_bounds__(256)
void transpose_w2(const float* __restrict__ W2, bf16* __restrict__ W2t, int e0)
{
    const int e  = e0 + blockIdx.z;
    const int oo = blockIdx.x;  // O/64
    const int ho = blockIdx.y;  // H/64
    const int tid = threadIdx.x;

    __shared__ bf16 t[64][68];

    const float* src = W2 + (size_t)e * H_ * O_ + (size_t)(ho * 64) * O_ + oo * 64;
#pragma unroll
    for (int p = 0; p < 4; ++p) {
        const int h  = p * 16 + (tid >> 4);
        const int o4 = (tid & 15) * 4;
        f32x4 v = *(const f32x4*)(src + (size_t)h * O_ + o4);
#pragma unroll
        for (int q = 0; q < 4; ++q) t[o4 + q][h] = (bf16)v[q];
    }
    __syncthreads();

    bf16* dst = W2t + (size_t)blockIdx.z * O_ * H_ + (size_t)(oo * 64) * H_ + ho * 64;
#pragma unroll
    for (int p = 0; p < 4; ++p) {
        const int o  = p * 16 + (tid >> 4);
        const int h4 = (tid & 15) * 4;
        bf16x4 v = *(const bf16x4*)(&t[o][h4]);
        *(bf16x4*)(dst + (size_t)o * H_ + h4) = v;
    }
}

// ---------------------------------------------------------------------------
// 256x256-tile 8-phase grouped GEMM (m201 template), BK=64, 2 K-tiles/iter.
// 512 thr = 8 waves (2M x 4N), wave tile 128x64, acc[8][4] f32x4.
// LDS 128 KiB: dbuf d in {0,1} (tile g -> dbuf g&1), each 64 KiB =
//   A-half0 @0, A-half1 @16K, B-half0 @32K, B-half1 @48K (half = 128 rows x
//   64 k x 2B = 16 KiB, rows x 128B).
// Swizzle: chunk c (16B units, 0..7 within a 128B row) stored at c^(row&7);
// applied on pre-swizzled global source (gload_lds writes linearly) and on
// the ds_read address -> conflict-free b128 fragment reads.
// Per phase: {ds_read subtile | stage 1 half-tile} -> barrier -> lgkmcnt(0)
// -> setprio(1) 16 MFMA setprio(0) -> [vmcnt(4) at ph3/ph7] -> barrier.
// Stage stream (iter t): ph0:A0(2t+1) ph1:A1(2t+1) ph2:B0(2t+2) ph3:B1(2t+2)
// ph4:A0(2t+2) ph5:A1(2t+2) ph6:B0(2t+3) ph7:B1(2t+3).  Each region's last
// ds_read drains (own-phase lgkmcnt) >=1 barrier before its restage issues.
// vmcnt(4)@ph3 retires tile 2t+1 fully (read ph4..7); vmcnt(4)@ph7 retires
// tile 2t+2 (read next iter ph0..3). Last iter: vmcnt(0)@ph3, no stages ph2+.
// ---------------------------------------------------------------------------
template<int KDIM, bool RELU_BF16>
__global__ __launch_bounds__(512, 2)
void gemm256(const bf16* __restrict__ A, const bf16* __restrict__ B,
             const float* __restrict__ bias, void* __restrict__ OutP,
             int nBM, int nBN)
{
    extern __shared__ char smem[];                  // 131072 B
    constexpr int K2  = KDIM * 2;                   // row stride bytes
    constexpr int NIT = KDIM / 128;                 // iterations (2 K-tiles each)

    const int tid  = threadIdx.x;
    const int lane = tid & 63;
    const int wid  = tid >> 6;
    const int wr = wid >> 2, wc = wid & 3;
    const int fr = lane & 15, fq = lane >> 4;

    // XCD-aware bijective block swizzle (grid % 8 == 0 by construction)
    const int nwg = gridDim.x;
    const int cpx = nwg >> 3;
    const int b0  = blockIdx.x;
    const int wg  = (b0 & 7) * cpx + (b0 >> 3);
    const int per_e = nBM * nBN;
    const int e  = wg / per_e;
    const int rr = wg - e * per_e;
    const int bn = rr / nBM;
    const int bm = rr - bn * nBM;
    const int MROWS = nBM * 256;
    const int NROWS = nBN * 256;

    const char* Apan = (const char*)(A + (size_t)e * MROWS * KDIM + (size_t)bm * 256 * KDIM);
    const char* Bpan = (const char*)(B + (size_t)e * NROWS * KDIM + (size_t)bn * 256 * KDIM);

    // staging geometry: thread covers rows r0 and r0+64 of a 128-row half,
    // chunk (tid&7); source chunk pre-swizzled by ^(row&7) (same for r0,r0+64)
    const int r0  = tid >> 3;                       // 0..63
    const int wsw = ((tid & 7) << 4) ^ ((r0 & 7) << 4);

    auto stage_half = [&](int g, int comp) {        // comp: 0=A0 1=A1 2=B0 3=B1
        char* lds = smem + (g & 1) * 65536 + comp * 16384 + tid * 16;
        const char* pan = (comp < 2) ? Apan : Bpan;
        const char* src = pan + (size_t)(((comp & 1) << 7) + r0) * K2
                              + (size_t)g * 128 + wsw;
        GLOAD16(src, lds);
        GLOAD16(src + (size_t)64 * K2, lds + 8192);
    };

    // fragment-read lane constants: chunk c = kk*4+fq, swizzled c^(fr&7)
    const int frq = fr & 7;
    const int cA0 = ((fq    ) ^ frq) << 4;
    const int cA1 = ((4 | fq) ^ frq) << 4;
    const int aoff = wr * 16384 + fr * 128;                         // A half sel + row
    const int boff = 32768 + (wc >> 1) * 16384 + (wc & 1) * 8192 + fr * 128;

    bf16x8 av[4][2];        // current A m-half frags (m' x kk)
    bf16x8 bv[4][2];        // all B frags (n x kk)
    f32x4 acc[8][4];
#pragma unroll
    for (int m = 0; m < 8; ++m)
#pragma unroll
        for (int n = 0; n < 4; ++n) acc[m][n] = (f32x4){0.f, 0.f, 0.f, 0.f};

    auto loadA = [&](const char* base, int mh) {
#pragma unroll
        for (int mm = 0; mm < 4; ++mm) {
            const char* p = base + aoff + (mh * 4 + mm) * 2048;
            av[mm][0] = *(const bf16x8*)(p + cA0);
            av[mm][1] = *(const bf16x8*)(p + cA1);
        }
    };
    auto loadB = [&](const char* base, int nh) {
#pragma unroll
        for (int nn = 0; nn < 2; ++nn) {
            const char* p = base + boff + (nh * 2 + nn) * 2048;
            bv[nh * 2 + nn][0] = *(const bf16x8*)(p + cA0);
            bv[nh * 2 + nn][1] = *(const bf16x8*)(p + cA1);
        }
    };
    auto mmaq = [&](int mh, int nh) {
        __builtin_amdgcn_s_setprio(1);
#pragma unroll
        for (int mm = 0; mm < 4; ++mm)
#pragma unroll
            for (int nn = 0; nn < 2; ++nn) {
                const int m = mh * 4 + mm, n = nh * 2 + nn;
                acc[m][n] = __builtin_amdgcn_mfma_f32_16x16x32_bf16(av[mm][0], bv[n][0], acc[m][n], 0, 0, 0);
                acc[m][n] = __builtin_amdgcn_mfma_f32_16x16x32_bf16(av[mm][1], bv[n][1], acc[m][n], 0, 0, 0);
            }
        __builtin_amdgcn_s_setprio(0);
    };

    // prologue: tile0 (B,B,A,A) + tile1 (B,B) = 12 loads; retire tile0
    stage_half(0, 2); stage_half(0, 3); stage_half(0, 0); stage_half(0, 1);
    stage_half(1, 2); stage_half(1, 3);
    VMCNT(4);
    BARRIER();

    for (int t = 0; t < NIT; ++t) {
        const bool nl = (t + 1 < NIT);
        const char* d0b = smem;             // tile 2t
        const char* d1b = smem + 65536;     // tile 2t+1
        const int ga = 2 * t + 1;
        const int gb = 2 * t + 2;
        const int gc = 2 * t + 3;

        // ---- K-tile a (dbuf0) ----
        loadB(d0b, 0); loadA(d0b, 0);       // ph0
        stage_half(ga, 0);
        BARRIER(); LGKM0();
        mmaq(0, 0);
        BARRIER();

        loadB(d0b, 1);                      // ph1
        stage_half(ga, 1);
        BARRIER(); LGKM0();
        mmaq(0, 1);
        BARRIER();

        loadA(d0b, 1);                      // ph2
        if (nl) stage_half(gb, 2);
        BARRIER(); LGKM0();
        mmaq(1, 1);
        BARRIER();

        if (nl) stage_half(gb, 3);          // ph3
        BARRIER(); LGKM0();
        mmaq(1, 0);
        if (nl) { VMCNT(4); } else { VMCNT(0); }   // tile 2t+1 fully resident
        BARRIER();

        // ---- K-tile b (dbuf1) ----
        loadB(d1b, 0); loadA(d1b, 0);       // ph4
        if (nl) stage_half(gb, 0);
        BARRIER(); LGKM0();
        mmaq(0, 0);
        BARRIER();

        loadB(d1b, 1);                      // ph5
        if (nl) stage_half(gb, 1);
        BARRIER(); LGKM0();
        mmaq(0, 1);
        BARRIER();

        loadA(d1b, 1);                      // ph6
        if (nl) stage_half(gc, 2);
        BARRIER(); LGKM0();
        mmaq(1, 1);
        BARRIER();

        if (nl) stage_half(gc, 3);          // ph7
        BARRIER(); LGKM0();
        mmaq(1, 0);
        if (nl) {
            VMCNT(4);                       // tile 2t+2 fully resident
            BARRIER();
        }
    }

    // epilogue
    const int gr0 = bm * 256 + wr * 128;
    const int gc0 = bn * 256 + wc * 64;
    if constexpr (RELU_BF16) {
        bf16* Out = (bf16*)OutP;
#pragma unroll
        for (int n = 0; n < 4; ++n) {
            const int col = gc0 + n * 16 + fr;
            const float bb = bias[(size_t)e * NROWS + col];
#pragma unroll
            for (int m = 0; m < 8; ++m)
#pragma unroll
                for (int j = 0; j < 4; ++j) {
                    float v = acc[m][n][j] + bb;
                    v = v > 0.f ? v : 0.f;
                    const int row = gr0 + m * 16 + fq * 4 + j;
                    Out[((size_t)e * MROWS + row) * NROWS + col] = (bf16)v;
                }
        }
    } else {
        float* Out = (float*)OutP;
#pragma unroll
        for (int n = 0; n < 4; ++n) {
            const int col = gc0 + n * 16 + fr;
            const float bb = bias[(size_t)e * NROWS + col];
#pragma unroll
            for (int m = 0; m < 8; ++m)
#pragma unroll
                for (int j = 0; j < 4; ++j) {
                    const int row = gr0 + m * 16 + fq * 4 + j;
                    Out[((size_t)e * MROWS + row) * NROWS + col] = acc[m][n][j] + bb;
                }
        }
    }
}

// ---------------------------------------------------------------------------
extern "C" void kernel_launch(void* const* d_in, const int* in_sizes, int n_in,
                              void* d_out, int out_size, void* d_ws, size_t ws_size,
                              hipStream_t stream)
{
    const float* x  = (const float*)d_in[0];
    const float* w1 = (const float*)d_in[1];
    const float* b1 = (const float*)d_in[2];
    const float* w2 = (const float*)d_in[3];
    const float* b2 = (const float*)d_in[4];
    float* out = (float*)d_out;

    (void)hipFuncSetAttribute(reinterpret_cast<const void*>(&gemm256<M_, true>),
                              hipFuncAttributeMaxDynamicSharedMemorySize, 131072);
    (void)hipFuncSetAttribute(reinterpret_cast<const void*>(&gemm256<H_, false>),
                              hipFuncAttributeMaxDynamicSharedMemorySize, 131072);

    const size_t xb_sz  = (size_t)E_ * C_ * M_ * sizeof(bf16);   //  32 MB
    const size_t w1b_sz = (size_t)E_ * H_ * M_ * sizeof(bf16);   // 256 MB
    const size_t w2t_sz = (size_t)E_ * O_ * H_ * sizeof(bf16);   // 256 MB
    const size_t y1_sz  = (size_t)E_ * C_ * H_ * sizeof(bf16);   // 128 MB

    if (ws_size >= xb_sz + w1b_sz + w2t_sz + y1_sz) {
        bf16* xb  = (bf16*)d_ws;
        bf16* w1b = (bf16*)((char*)d_ws + xb_sz);
        bf16* w2t = (bf16*)((char*)d_ws + xb_sz + w1b_sz);
        bf16* y1  = (bf16*)((char*)d_ws + xb_sz + w1b_sz + w2t_sz);

        cvt_f32_bf16<<<2048, 256, 0, stream>>>(x,  xb,  (size_t)E_ * C_ * M_);
        cvt_f32_bf16<<<2048, 256, 0, stream>>>(w1, w1b, (size_t)E_ * H_ * M_);
        transpose_w2<<<dim3(O_ / 64, H_ / 64, E_), 256, 0, stream>>>(w2, w2t, 0);

        gemm256<M_, true><<<dim3(8 * 4 * (H_ / 256)), 512, 131072, stream>>>(
            xb, w1b, b1, y1, 4, H_ / 256);
        gemm256<H_, false><<<dim3(8 * 4 * (O_ / 256)), 512, 131072, stream>>>(
            y1, w2t, b2, out, 4, O_ / 256);
    } else {
        // per-expert fallback: ~84 MB of ws
        bf16* xb  = (bf16*)d_ws;
        bf16* w1b = (bf16*)((char*)d_ws + xb_sz / E_);
        bf16* w2t = (bf16*)((char*)d_ws + (xb_sz + w1b_sz) / E_);
        bf16* y1  = (bf16*)((char*)d_ws + (xb_sz + w1b_sz + w2t_sz) / E_);
        for (int e = 0; e < E_; ++e) {
            cvt_f32_bf16<<<512, 256, 0, stream>>>(x + (size_t)e * C_ * M_,  xb,  (size_t)C_ * M_);
            cvt_f32_bf16<<<2048, 256, 0, stream>>>(w1 + (size_t)e * H_ * M_, w1b, (size_t)H_ * M_);
            transpose_w2<<<dim3(O_ / 64, H_ / 64, 1), 256, 0, stream>>>(w2, w2t, e);
            gemm256<M_, true><<<dim3(4 * (H_ / 256)), 512, 131072, stream>>>(
                xb, w1b, b1 + (size_t)e * H_, y1, 4, H_ / 256);
            gemm256<H_, false><<<dim3(4 * (O_ / 256)), 512, 131072, stream>>>(
                y1, w2t, b2 + (size_t)e * O_, out + (size_t)e * C_ * O_, 4, O_ / 256);
        }
    }
}